// Round 10
// baseline (79.925 us; speedup 1.0000x reference)
//
#include <hip/hip_runtime.h>

// SSIM via MFMA: both separable 11-tap Gaussian passes are matmuls by a
// constant banded matrix (f16 inputs, f32 accumulate). V-pass computed
// transposed so each lane's V output IS the H-pass A-fragment (R7/R8
// verified). f16-weight-sum scale corrected by 1/t (R8).
// R10: per-block software pipeline over 4 stacked 64x64 tiles. Loads for
// tile t+1 are issued into REGISTERS (52 f32/thread, coalesced) before
// compute(t) so HBM latency hides under MFMA+ssim; commit (cvt+ds_write)
// runs after the barrier. R8/R9 showed occupancy is not the limiter
// (25%->39% occ, flat 50-52us, VGPR=40 = serialized stage loop); this
// attacks the per-wave latency chain directly.

typedef _Float16 f16;
typedef __attribute__((ext_vector_type(4))) _Float16 f16x4;
typedef __attribute__((ext_vector_type(8))) _Float16 f16x8;
typedef __attribute__((ext_vector_type(4))) float f32x4;

#define IMGW 512
#define IMGH 512
#define NPL 48           // 16*3 planes
#define PT 4             // tiles per block, stacked vertically
#define NBLOCKS (NPL * 8 * 2)   // 768 = planes x 8 col-tiles x 2 row-halves
#define NPIX 12582912.0
#define REDT 1024

#define SR 84            // LDS row-stride (f16) per column slot (bank pad)
#define NC 80            // staged cols per image
#define IMGOFF (NC * SR) // 6720 f16 per image

// inverse of total f16-weight scale: s = sum of f16(G) = 1048748/2^20, t = s^2
#define INV_T 0.99967202f

// 11-tap gaussian, sigma=1.5, normalized (double-precision precomputed)
__device__ const float G_dev[11] = {0.00102838f, 0.00759876f, 0.03600077f,
                                    0.10936069f, 0.21300554f, 0.26601172f,
                                    0.21300554f, 0.10936069f, 0.03600077f,
                                    0.00759876f, 0.00102838f};

// ---- issue: fire the 80x80x2 patch loads (coalesced scalar) into regs ----
template<bool EDGE>
__device__ __forceinline__ void issue(const float* __restrict__ p1,
                                      const float* __restrict__ p2,
                                      int R0, int AC0, int tid, float v[13][4]) {
    #pragma unroll
    for (int it = 0; it < 13; ++it) {
        if (it == 12 && tid >= 128) break;      // 3200 tasks total
        const int idx  = tid + it * 256;
        const int img  = (idx >= 1600) ? 1 : 0;
        const int rem  = idx - img * 1600;
        const int g    = rem / NC;              // row group 0..19
        const int lcol = rem - g * NC;          // staged col 0..79
        const float* __restrict__ base = img ? p2 : p1;
        const int gc = AC0 + lcol;
        const int gr = R0 + 4 * g;
        if (EDGE) {
            const bool cok = ((unsigned)gc < (unsigned)IMGW);
            const int cc = cok ? gc : 0;
            #pragma unroll
            for (int e = 0; e < 4; ++e) {
                const int r  = gr + e;
                const bool ok = cok && ((unsigned)r < (unsigned)IMGH);
                const int rc = (r < 0) ? 0 : (r > IMGH - 1 ? IMGH - 1 : r);
                const float x = base[(size_t)rc * IMGW + cc];
                v[it][e] = ok ? x : 0.0f;
            }
        } else {
            #pragma unroll
            for (int e = 0; e < 4; ++e)
                v[it][e] = base[(size_t)(gr + e) * IMGW + gc];
        }
    }
}

// ---- commit: vmcnt-wait (implicit), cvt f16, transposed b64 LDS write ----
__device__ __forceinline__ void commit(const float v[13][4], int tid, f16* sT) {
    #pragma unroll
    for (int it = 0; it < 13; ++it) {
        if (it == 12 && tid >= 128) break;
        const int idx  = tid + it * 256;
        const int img  = (idx >= 1600) ? 1 : 0;
        const int rem  = idx - img * 1600;
        const int g    = rem / NC;
        const int lcol = rem - g * NC;
        const f16x4 h = {(f16)v[it][0], (f16)v[it][1], (f16)v[it][2], (f16)v[it][3]};
        *(f16x4*)&sT[(size_t)img * IMGOFF + (size_t)lcol * SR + 4 * g] = h;
    }
}

// ---- compute: V-pass (transposed mfma) -> H-pass -> ssim, one 64x64 tile ----
__device__ __forceinline__ float compute_tile(const f16* sT, int wv, int l15,
                                              int lg, f16x8 bband) {
    const f32x4 zero4 = {0.0f, 0.0f, 0.0f, 0.0f};
    f16x4 hv[5][5];    // [chunk][quantity: x,y,xx,yy,xy]
    #pragma unroll
    for (int t = 0; t < 5; ++t) {
        int col = 3 + 16 * t + l15;
        if (t == 4) col = (col > NC - 1) ? NC - 1 : col;   // dead vcols >73
        const int ro = 16 * wv + 4 * lg;
        const f16* __restrict__ cb1 = sT + (size_t)col * SR;
        const f16* __restrict__ cb2 = sT + IMGOFF + (size_t)col * SR;
        const f16x4 xlo = *(const f16x4*)&cb1[ro];
        const f16x4 xhi = *(const f16x4*)&cb1[ro + 16];
        const f16x4 ylo = *(const f16x4*)&cb2[ro];
        const f16x4 yhi = *(const f16x4*)&cb2[ro + 16];
        const f16x8 fx = __builtin_shufflevector(xlo, xhi, 0, 1, 2, 3, 4, 5, 6, 7);
        const f16x8 fy = __builtin_shufflevector(ylo, yhi, 0, 1, 2, 3, 4, 5, 6, 7);
        const f16x8 fxx = fx * fx;   // v_pk_mul_f16
        const f16x8 fyy = fy * fy;
        const f16x8 fxy = fx * fy;

        const f32x4 dx  = __builtin_amdgcn_mfma_f32_16x16x32_f16(fx,  bband, zero4, 0, 0, 0);
        const f32x4 dy  = __builtin_amdgcn_mfma_f32_16x16x32_f16(fy,  bband, zero4, 0, 0, 0);
        const f32x4 dxx = __builtin_amdgcn_mfma_f32_16x16x32_f16(fxx, bband, zero4, 0, 0, 0);
        const f32x4 dyy = __builtin_amdgcn_mfma_f32_16x16x32_f16(fyy, bband, zero4, 0, 0, 0);
        const f32x4 dxy = __builtin_amdgcn_mfma_f32_16x16x32_f16(fxy, bband, zero4, 0, 0, 0);

        hv[t][0] = (f16x4){(f16)dx[0],  (f16)dx[1],  (f16)dx[2],  (f16)dx[3]};
        hv[t][1] = (f16x4){(f16)dy[0],  (f16)dy[1],  (f16)dy[2],  (f16)dy[3]};
        hv[t][2] = (f16x4){(f16)dxx[0], (f16)dxx[1], (f16)dxx[2], (f16)dxx[3]};
        hv[t][3] = (f16x4){(f16)dyy[0], (f16)dyy[1], (f16)dyy[2], (f16)dyy[3]};
        hv[t][4] = (f16x4){(f16)dxy[0], (f16)dxy[1], (f16)dxy[2], (f16)dxy[3]};
    }

    float acc = 0.0f;
    const float C1 = 1.0e-4f;   // 0.01^2
    const float C2 = 9.0e-4f;   // 0.03^2
    #pragma unroll
    for (int m = 0; m < 4; ++m) {
        f32x4 h[5];
        #pragma unroll
        for (int q = 0; q < 5; ++q) {
            const f16x8 a = __builtin_shufflevector(hv[m][q], hv[m + 1][q],
                                                    0, 1, 2, 3, 4, 5, 6, 7);
            h[q] = __builtin_amdgcn_mfma_f32_16x16x32_f16(a, bband, zero4, 0, 0, 0);
            h[q] *= INV_T;   // remove f16-weight-sum scale (s^2 per quantity)
        }
        #pragma unroll
        for (int r = 0; r < 4; ++r) {
            const float mu1 = h[0][r], mu2 = h[1][r];
            const float exx = h[2][r], eyy = h[3][r], exy = h[4][r];
            const float mu1s = mu1 * mu1;
            const float mu2s = mu2 * mu2;
            const float mu12 = mu1 * mu2;
            const float s1  = exx - mu1s;
            const float s2  = eyy - mu2s;
            const float s12 = exy - mu12;
            const float num = fmaf(2.0f, mu12, C1) * fmaf(2.0f, s12, C2);
            const float den = (mu1s + mu2s + C1) * (s1 + s2 + C2);
            float rd = __builtin_amdgcn_rcpf(den);   // den > 0 always
            rd = rd * fmaf(-den, rd, 2.0f);          // Newton step
            acc = fmaf(num, rd, acc);
        }
    }
    return acc;
}

__global__ __launch_bounds__(256, 3) void ssim_main(const float* __restrict__ img1,
                                                    const float* __restrict__ img2,
                                                    float* __restrict__ partial) {
    __shared__ f16 sT[2 * IMGOFF];     // 26880 B, transposed: [img][col][row]
    __shared__ float wsum[4];

    const int tid  = threadIdx.x;
    const int lane = tid & 63;
    const int wv   = tid >> 6;
    const int l15  = lane & 15;
    const int lg   = lane >> 4;

    const int bid   = blockIdx.x;
    const int plane = bid >> 4;             // 16 block-tiles per plane
    const int rem   = bid & 15;
    const int half  = rem >> 3;             // row half 0..1 (256 rows each)
    const int bx    = rem & 7;              // col tile 0..7
    const int c0    = bx * 64;
    const int AC0   = c0 - 8;               // staged col 0 (16B-aligned)
    const bool colEdge = (bx == 0) || (bx == 7);

    const float* __restrict__ p1 = img1 + (size_t)plane * (IMGH * IMGW);
    const float* __restrict__ p2 = img2 + (size_t)plane * (IMGH * IMGW);

    // constant band fragment: B[k][n] = G[kap(k) - n], n = l15
    // kap[j] = 4lg+j (j<4), 16+4lg+(j-4) (j>=4)
    f16x8 bband;
    #pragma unroll
    for (int j = 0; j < 8; ++j) {
        const int kj = (j < 4) ? (4 * lg + j) : (16 + 4 * lg + (j - 4));
        const int t  = kj - l15;
        const float w = (t >= 0 && t < 11) ? G_dev[t] : 0.0f;
        bband[j] = (f16)w;
    }

    float v[13][4];    // in-flight patch (held across compute of prev tile)
    float acc = 0.0f;

    // prologue: issue tile 0
    {
        const int R0 = half * 256 - 5;
        if (colEdge || half == 0) issue<true >(p1, p2, R0, AC0, tid, v);
        else                      issue<false>(p1, p2, R0, AC0, tid, v);
    }

    #pragma unroll
    for (int t = 0; t < PT; ++t) {
        commit(v, tid, sT);                 // waits vmcnt, cvt+write LDS
        __syncthreads();                    // LDS tile visible
        if (t < PT - 1) {                   // fire next tile's loads NOW
            const int R0n = half * 256 + (t + 1) * 64 - 5;
            const bool en = colEdge || (half == 1 && t + 1 == PT - 1);
            if (en) issue<true >(p1, p2, R0n, AC0, tid, v);
            else    issue<false>(p1, p2, R0n, AC0, tid, v);
        }
        acc += compute_tile(sT, wv, l15, lg, bband);   // overlaps loads
        __syncthreads();                    // reads done before next commit
    }

    // block reduction
    #pragma unroll
    for (int off = 32; off > 0; off >>= 1)
        acc += __shfl_down(acc, off, 64);
    if (lane == 0) wsum[wv] = acc;
    __syncthreads();
    if (tid == 0)
        partial[bid] = (wsum[0] + wsum[1]) + (wsum[2] + wsum[3]);
}

__global__ __launch_bounds__(REDT) void ssim_reduce(const float* __restrict__ partial,
                                                    float* __restrict__ out) {
    const int tid = threadIdx.x;
    double s = 0.0;
    for (int i = tid; i < NBLOCKS; i += REDT)
        s += (double)partial[i];
    #pragma unroll
    for (int off = 32; off > 0; off >>= 1)
        s += __shfl_down(s, off, 64);
    __shared__ double wsd[REDT / 64];
    if ((tid & 63) == 0) wsd[tid >> 6] = s;
    __syncthreads();
    if (tid == 0) {
        double t = 0.0;
        #pragma unroll
        for (int i = 0; i < REDT / 64; ++i) t += wsd[i];
        out[0] = (float)(t / NPIX);
    }
}

extern "C" void kernel_launch(void* const* d_in, const int* in_sizes, int n_in,
                              void* d_out, int out_size, void* d_ws, size_t ws_size,
                              hipStream_t stream) {
    const float* img1 = (const float*)d_in[0];
    const float* img2 = (const float*)d_in[1];
    float* partial = (float*)d_ws;      // 768 floats
    float* out = (float*)d_out;
    ssim_main<<<NBLOCKS, 256, 0, stream>>>(img1, img2, partial);
    ssim_reduce<<<1, REDT, 0, stream>>>(partial, out);
}

// Round 11
// 49.993 us; speedup vs baseline: 1.5987x; 1.5987x over previous
//
#include <hip/hip_runtime.h>

// SSIM via MFMA: both separable 11-tap Gaussian passes are matmuls by a
// constant banded matrix (f16 inputs, f32 accumulate). V-pass computed
// transposed so each lane's V output IS the H-pass A-fragment (R7/R8
// verified). f16-weight-sum scale corrected by 1/t (R8).
// R11: R9 structure, but staging is software-pipelined at BATCH granularity:
// two named register batches (12/16 floats) with issue/commit interleaved
// 2-deep, so ~13 serial HBM-latency exposures collapse to ~4 while peak
// live regs stay ~28 (R10's 52-float version spilled: WRITE 70 MB, 100us).
// Edge zero-select moved to commit (loads use clamped in-bounds addresses).
// launch_bounds(256,5): VGPR cap 102, 5 blocks/CU (LDS 27136 B x 5 fits).

typedef _Float16 f16;
typedef __attribute__((ext_vector_type(4))) _Float16 f16x4;
typedef __attribute__((ext_vector_type(8))) _Float16 f16x8;
typedef __attribute__((ext_vector_type(4))) float f32x4;

#define IMGW 512
#define IMGH 512
#define NPL 48           // 16*3 planes
#define NBLOCKS (NPL * 8 * 8)   // 3072: 64x64 tile per block
#define NPIX 12582912.0
#define REDT 1024

#define SR 84            // LDS row-stride (f16) per column slot (bank pad)
#define NC 80            // staged cols per image
#define IMGOFF (NC * SR) // 6720 f16 per image

// inverse of total f16-weight scale: s = sum of f16(G) = 1048748/2^20, t = s^2
#define INV_T 0.99967202f

// 11-tap gaussian, sigma=1.5, normalized (double-precision precomputed)
__device__ const float G_dev[11] = {0.00102838f, 0.00759876f, 0.03600077f,
                                    0.10936069f, 0.21300554f, 0.26601172f,
                                    0.21300554f, 0.10936069f, 0.03600077f,
                                    0.00759876f, 0.00102838f};

// ---- issue a batch of staging iterations: pure loads into registers ----
// task idx = tid + it*256; img = idx>=1600; within image: row-group g (4
// rows), col lcol. Consecutive lanes -> consecutive cols (256B/wave-load).
template<bool EDGE, int BASE, int CNT>
__device__ __forceinline__ void issue_b(const float* __restrict__ p1,
                                        const float* __restrict__ p2,
                                        int R0, int AC0, int tid,
                                        float (*v)[4]) {
    #pragma unroll
    for (int ii = 0; ii < CNT; ++ii) {
        const int it = BASE + ii;
        if (it == 12 && tid >= 128) continue;   // wave-uniform tail
        const int idx  = tid + it * 256;
        const int img  = (idx >= 1600) ? 1 : 0;
        const int rem  = idx - img * 1600;
        const int g    = rem / NC;              // row group 0..19
        const int lcol = rem - g * NC;          // staged col 0..79
        const float* __restrict__ bp = img ? p2 : p1;
        const int gc = AC0 + lcol;
        const int gr = R0 + 4 * g;
        if (EDGE) {
            const int cc = ((unsigned)gc < (unsigned)IMGW) ? gc : 0;
            #pragma unroll
            for (int e = 0; e < 4; ++e) {
                const int r  = gr + e;
                const int rc = (r < 0) ? 0 : (r > IMGH - 1 ? IMGH - 1 : r);
                v[ii][e] = bp[(size_t)rc * IMGW + cc];   // always in-bounds
            }
        } else {
            #pragma unroll
            for (int e = 0; e < 4; ++e)
                v[ii][e] = bp[(size_t)(gr + e) * IMGW + gc];
        }
    }
}

// ---- commit a batch: (edge zero-select), cvt f16, transposed b64 write ----
template<bool EDGE, int BASE, int CNT>
__device__ __forceinline__ void commit_b(int R0, int AC0, int tid,
                                         const float (*v)[4], f16* sT) {
    #pragma unroll
    for (int ii = 0; ii < CNT; ++ii) {
        const int it = BASE + ii;
        if (it == 12 && tid >= 128) continue;
        const int idx  = tid + it * 256;
        const int img  = (idx >= 1600) ? 1 : 0;
        const int rem  = idx - img * 1600;
        const int g    = rem / NC;
        const int lcol = rem - g * NC;
        float x[4];
        #pragma unroll
        for (int e = 0; e < 4; ++e) {
            x[e] = v[ii][e];
            if (EDGE) {
                const int gc = AC0 + lcol;
                const int r  = R0 + 4 * g + e;
                const bool ok = ((unsigned)gc < (unsigned)IMGW) &&
                                ((unsigned)r  < (unsigned)IMGH);
                x[e] = ok ? x[e] : 0.0f;
            }
        }
        const f16x4 h = {(f16)x[0], (f16)x[1], (f16)x[2], (f16)x[3]};
        *(f16x4*)&sT[(size_t)img * IMGOFF + (size_t)lcol * SR + 4 * g] = h;
    }
}

// ---- staging: 2-deep batch pipeline (peak ~28 floats in flight) ----
template<bool EDGE>
__device__ __forceinline__ void stage(const float* __restrict__ p1,
                                      const float* __restrict__ p2,
                                      int R0, int AC0, int tid, f16* sT) {
    float va[3][4], vb[4][4];
    issue_b <EDGE, 0, 3>(p1, p2, R0, AC0, tid, va);
    issue_b <EDGE, 3, 3>(p1, p2, R0, AC0, tid, vb);
    commit_b<EDGE, 0, 3>(R0, AC0, tid, va, sT);
    issue_b <EDGE, 6, 3>(p1, p2, R0, AC0, tid, va);
    commit_b<EDGE, 3, 3>(R0, AC0, tid, vb, sT);
    issue_b <EDGE, 9, 4>(p1, p2, R0, AC0, tid, vb);
    commit_b<EDGE, 6, 3>(R0, AC0, tid, va, sT);
    commit_b<EDGE, 9, 4>(R0, AC0, tid, vb, sT);
}

__global__ __launch_bounds__(256, 5) void ssim_main(const float* __restrict__ img1,
                                                    const float* __restrict__ img2,
                                                    float* __restrict__ partial) {
    __shared__ f16 sT[2 * IMGOFF];     // 26880 B, transposed: [img][col][row]
    __shared__ float wsum[4];

    const int tid  = threadIdx.x;
    const int lane = tid & 63;
    const int wv   = tid >> 6;         // wave 0..3 (stacked vertically)
    const int l15  = lane & 15;
    const int lg   = lane >> 4;        // 0..3

    const int bid   = blockIdx.x;
    const int plane = bid >> 6;        // 64 tiles per plane
    const int rem   = bid & 63;
    const int by    = rem >> 3;
    const int bx    = rem & 7;
    const int R0    = by * 64 - 5;          // staged row 0
    const int AC0   = bx * 64 - 8;          // staged col 0 (16B-aligned)

    const float* __restrict__ p1 = img1 + (size_t)plane * (IMGH * IMGW);
    const float* __restrict__ p2 = img2 + (size_t)plane * (IMGH * IMGW);

    // ---------- stage both images (transposed f16, pipelined) ----------
    if (by >= 1 && by <= 6 && bx >= 1 && bx <= 6)
        stage<false>(p1, p2, R0, AC0, tid, sT);
    else
        stage<true >(p1, p2, R0, AC0, tid, sT);
    __syncthreads();

    // constant band fragment: B[k][n] = G[kap(k) - n], n = l15
    // kap[j] = 4lg+j (j<4), 16+4lg+(j-4) (j>=4)
    f16x8 bband;
    #pragma unroll
    for (int j = 0; j < 8; ++j) {
        const int kj = (j < 4) ? (4 * lg + j) : (16 + 4 * lg + (j - 4));
        const int t  = kj - l15;
        const float w = (t >= 0 && t < 11) ? G_dev[t] : 0.0f;
        bband[j] = (f16)w;
    }

    const f32x4 zero4 = {0.0f, 0.0f, 0.0f, 0.0f};

    // ---------- V-pass: A[i=vcol][k=row-slot] from LDS, transposed mfma ----------
    f16x4 hv[5][5];    // [chunk][quantity: x,y,xx,yy,xy]
    #pragma unroll
    for (int t = 0; t < 5; ++t) {
        int col = 3 + 16 * t + l15;
        if (t == 4) col = (col > NC - 1) ? NC - 1 : col;   // dead vcols >73
        const int ro = 16 * wv + 4 * lg;
        const f16* __restrict__ cb1 = sT + (size_t)col * SR;
        const f16* __restrict__ cb2 = sT + IMGOFF + (size_t)col * SR;
        const f16x4 xlo = *(const f16x4*)&cb1[ro];
        const f16x4 xhi = *(const f16x4*)&cb1[ro + 16];
        const f16x4 ylo = *(const f16x4*)&cb2[ro];
        const f16x4 yhi = *(const f16x4*)&cb2[ro + 16];
        const f16x8 fx = __builtin_shufflevector(xlo, xhi, 0, 1, 2, 3, 4, 5, 6, 7);
        const f16x8 fy = __builtin_shufflevector(ylo, yhi, 0, 1, 2, 3, 4, 5, 6, 7);
        const f16x8 fxx = fx * fx;   // v_pk_mul_f16
        const f16x8 fyy = fy * fy;
        const f16x8 fxy = fx * fy;

        const f32x4 dx  = __builtin_amdgcn_mfma_f32_16x16x32_f16(fx,  bband, zero4, 0, 0, 0);
        const f32x4 dy  = __builtin_amdgcn_mfma_f32_16x16x32_f16(fy,  bband, zero4, 0, 0, 0);
        const f32x4 dxx = __builtin_amdgcn_mfma_f32_16x16x32_f16(fxx, bband, zero4, 0, 0, 0);
        const f32x4 dyy = __builtin_amdgcn_mfma_f32_16x16x32_f16(fyy, bband, zero4, 0, 0, 0);
        const f32x4 dxy = __builtin_amdgcn_mfma_f32_16x16x32_f16(fxy, bband, zero4, 0, 0, 0);

        hv[t][0] = (f16x4){(f16)dx[0],  (f16)dx[1],  (f16)dx[2],  (f16)dx[3]};
        hv[t][1] = (f16x4){(f16)dy[0],  (f16)dy[1],  (f16)dy[2],  (f16)dy[3]};
        hv[t][2] = (f16x4){(f16)dxx[0], (f16)dxx[1], (f16)dxx[2], (f16)dxx[3]};
        hv[t][3] = (f16x4){(f16)dyy[0], (f16)dyy[1], (f16)dyy[2], (f16)dyy[3]};
        hv[t][4] = (f16x4){(f16)dxy[0], (f16)dxy[1], (f16)dxy[2], (f16)dxy[3]};
    }

    // ---------- H-pass + ssim ----------
    float acc = 0.0f;
    const float C1 = 1.0e-4f;   // 0.01^2
    const float C2 = 9.0e-4f;   // 0.03^2
    #pragma unroll
    for (int m = 0; m < 4; ++m) {
        f32x4 h[5];
        #pragma unroll
        for (int q = 0; q < 5; ++q) {
            const f16x8 a = __builtin_shufflevector(hv[m][q], hv[m + 1][q],
                                                    0, 1, 2, 3, 4, 5, 6, 7);
            h[q] = __builtin_amdgcn_mfma_f32_16x16x32_f16(a, bband, zero4, 0, 0, 0);
            h[q] *= INV_T;   // remove f16-weight-sum scale (s^2 per quantity)
        }
        #pragma unroll
        for (int r = 0; r < 4; ++r) {
            const float mu1 = h[0][r], mu2 = h[1][r];
            const float exx = h[2][r], eyy = h[3][r], exy = h[4][r];
            const float mu1s = mu1 * mu1;
            const float mu2s = mu2 * mu2;
            const float mu12 = mu1 * mu2;
            const float s1  = exx - mu1s;
            const float s2  = eyy - mu2s;
            const float s12 = exy - mu12;
            const float num = fmaf(2.0f, mu12, C1) * fmaf(2.0f, s12, C2);
            const float den = (mu1s + mu2s + C1) * (s1 + s2 + C2);
            float rd = __builtin_amdgcn_rcpf(den);   // den > 0 always
            rd = rd * fmaf(-den, rd, 2.0f);          // Newton step
            acc = fmaf(num, rd, acc);
        }
    }

    // ---------- block reduction ----------
    #pragma unroll
    for (int off = 32; off > 0; off >>= 1)
        acc += __shfl_down(acc, off, 64);
    if (lane == 0) wsum[wv] = acc;
    __syncthreads();
    if (tid == 0)
        partial[bid] = (wsum[0] + wsum[1]) + (wsum[2] + wsum[3]);
}

__global__ __launch_bounds__(REDT) void ssim_reduce(const float* __restrict__ partial,
                                                    float* __restrict__ out) {
    const int tid = threadIdx.x;
    double s = 0.0;
    for (int i = tid; i < NBLOCKS; i += REDT)
        s += (double)partial[i];
    #pragma unroll
    for (int off = 32; off > 0; off >>= 1)
        s += __shfl_down(s, off, 64);
    __shared__ double wsd[REDT / 64];
    if ((tid & 63) == 0) wsd[tid >> 6] = s;
    __syncthreads();
    if (tid == 0) {
        double t = 0.0;
        #pragma unroll
        for (int i = 0; i < REDT / 64; ++i) t += wsd[i];
        out[0] = (float)(t / NPIX);
    }
}

extern "C" void kernel_launch(void* const* d_in, const int* in_sizes, int n_in,
                              void* d_out, int out_size, void* d_ws, size_t ws_size,
                              hipStream_t stream) {
    const float* img1 = (const float*)d_in[0];
    const float* img2 = (const float*)d_in[1];
    float* partial = (float*)d_ws;      // 3072 floats
    float* out = (float*)d_out;
    ssim_main<<<NBLOCKS, 256, 0, stream>>>(img1, img2, partial);
    ssim_reduce<<<1, REDT, 0, stream>>>(partial, out);
}